// Round 23
// baseline (155.611 us; speedup 1.0000x reference)
//
#include <hip/hip_runtime.h>

#define NUM_CODES 1296
#define PAD_CODES 1344    // 14 chunks * 96 (pads duplicate code 1295)
#define DDIM 64
#define NUM_Q 131072      // 32*64*64
#define THREADS 256       // 4 waves
#define WAVES 4
#define QPW 32            // queries per wave
#define QPB 128           // queries per block; 1024 blocks
#define MARGIN 0.25f      // certified: 2*alpha <= 0.16 (bf16 screen) + headroom
#define SLOTS 24          // per-query candidate slots (overflow -> exact scan)
#define CHUNK 96          // codes per LDS chunk (12288 B)
#define NSTEP 14          // PAD_CODES / CHUNK

typedef __attribute__((ext_vector_type(8))) short bf16x8;
typedef __attribute__((ext_vector_type(4))) float f32x4;

__device__ __forceinline__ ushort f2bf(float f) {   // fp32 -> bf16 RNE
    unsigned u = __float_as_uint(f);
    return (ushort)((u + 0x7fffu + ((u >> 16) & 1u)) >> 16);
}

// enorm (exact numpy pairwise chain) + bf16 embeddings, slot-swizzled:
// 16B slot s (0..7) of code k stored at halfword k*64 + (s^(k&7))*8.
__global__ __launch_bounds__(64) void vq_prep(const float* __restrict__ emb,
                                              float* __restrict__ enorm,
                                              ushort* __restrict__ eh) {
    int k = blockIdx.x * 64 + threadIdx.x;
    if (k >= PAD_CODES) return;
    int ks = k < NUM_CODES ? k : NUM_CODES - 1;
    const float* e = emb + (size_t)ks * DDIM;
    float f[DDIM];
#pragma unroll
    for (int i = 0; i < 16; ++i) {
        float4 v = *(const float4*)(e + 4 * i);
        f[4*i] = v.x; f[4*i+1] = v.y; f[4*i+2] = v.z; f[4*i+3] = v.w;
    }
    {
#pragma clang fp contract(off)
        float r8[8];
#pragma unroll
        for (int j = 0; j < 8; ++j) { float t = f[j] * f[j]; r8[j] = t; }
#pragma unroll
        for (int i = 1; i < 8; ++i) {
#pragma unroll
            for (int j = 0; j < 8; ++j) { float t = f[i*8+j] * f[i*8+j]; r8[j] += t; }
        }
        enorm[k] = ((r8[0]+r8[1])+(r8[2]+r8[3])) + ((r8[4]+r8[5])+(r8[6]+r8[7]));
    }
    ushort h[DDIM];
#pragma unroll
    for (int d = 0; d < DDIM; ++d) h[d] = f2bf(f[d]);
    uint* dh = (uint*)(eh + (size_t)k * DDIM);
#pragma unroll
    for (int s = 0; s < 8; ++s) {
        int ds = s ^ (k & 7);
#pragma unroll
        for (int j = 0; j < 4; ++j)
            dh[ds*4 + j] = (uint)h[s*8 + 2*j] | ((uint)h[s*8 + 2*j + 1] << 16);
    }
}

// ||x||^2 per query, exact numpy pairwise chain (for the rescore formula).
__global__ __launch_bounds__(256) void vq_xnorm(const float* __restrict__ x,
                                                float* __restrict__ xnorm) {
    int q = blockIdx.x * 256 + threadIdx.x;
    const float* r = x + (size_t)q * DDIM;
    float f[DDIM];
#pragma unroll
    for (int i = 0; i < 16; ++i) {
        float4 v = *(const float4*)(r + 4 * i);
        f[4*i] = v.x; f[4*i+1] = v.y; f[4*i+2] = v.z; f[4*i+3] = v.w;
    }
    {
#pragma clang fp contract(off)
        float r8[8];
#pragma unroll
        for (int j = 0; j < 8; ++j) { float t = f[j] * f[j]; r8[j] = t; }
#pragma unroll
        for (int i = 1; i < 8; ++i) {
#pragma unroll
            for (int j = 0; j < 8; ++j) { float t = f[i*8+j] * f[i*8+j]; r8[j] += t; }
        }
        xnorm[q] = ((r8[0]+r8[1])+(r8[2]+r8[3])) + ((r8[4]+r8[5])+(r8[6]+r8[7]));
    }
}

// Single-sweep LDS-staged bf16 MFMA screen with STALE-threshold bitmask
// candidate detection (acc dies per-tile; branch-free hot loop) + exact
// fp32 rescore. Certificate: s~(c*) <= rmin(any prefix) + MARGIN.
__global__ __launch_bounds__(THREADS) void vq_main(
        const float* __restrict__ x, const float* __restrict__ emb,
        const float* __restrict__ enorm_g, const float* __restrict__ xnorm,
        const ushort* __restrict__ eh, float* __restrict__ out) {
    __shared__ ushort sbuf[2][CHUNK * DDIM];        // 24576 B
    __shared__ ushort wq[WAVES][QPW * SLOTS];       // 6144 B
    __shared__ unsigned qcnt[WAVES][QPW];           // 512 B
    __shared__ unsigned skk[WAVES][QPW];            // 512 B  -> 31744 B total

    const int tid  = threadIdx.x;
    const int lane = tid & 63;
    const int w    = tid >> 6;
    const int cl   = lane & 15;          // MFMA col = code-in-tile
    const int g    = lane >> 4;          // k-slice / D-row group
    const long qw  = (long)blockIdx.x * QPB + w * QPW;

    if (lane < QPW) qcnt[w][lane] = 0;

    // A-frags (persistent): rows qw+cl / qw+16+cl; k slices [g*8,+8) and +32
    bf16x8 a00, a01, a10, a11;
    {
        const float* xp0 = x + (qw + cl) * DDIM + g * 8;
        const float* xp1 = xp0 + 16 * DDIM;
#pragma unroll
        for (int j = 0; j < 8; ++j) {
            a00[j] = (short)f2bf(xp0[j]);
            a01[j] = (short)f2bf(xp0[j + 32]);
            a10[j] = (short)f2bf(xp1[j]);
            a11[j] = (short)f2bf(xp1[j + 32]);
        }
    }

    float rmin0[4], rmin1[4];
#pragma unroll
    for (int r = 0; r < 4; ++r) { rmin0[r] = __builtin_inff(); rmin1[r] = __builtin_inff(); }

    const int slot0 = (g     ^ (cl & 7)) * 8;   // swizzled halfword offsets
    const int slot1 = ((g+4) ^ (cl & 7)) * 8;
    const f32x4 z4 = {0.f, 0.f, 0.f, 0.f};

    {   // prologue: stage chunk 0 (768 float4 over 256 threads)
        const float4* src = (const float4*)eh;
        float4 s0 = src[tid], s1 = src[256 + tid], s2 = src[512 + tid];
        *(float4*)&sbuf[0][(size_t)tid * 8]         = s0;
        *(float4*)&sbuf[0][(size_t)(256 + tid) * 8] = s1;
        *(float4*)&sbuf[0][(size_t)(512 + tid) * 8] = s2;
    }
    __syncthreads();

    float thrS0[4], thrS1[4];   // stale thresholds (certified conservative)

    {   // ---- bootstrap: chunk-0 score-only prepass -> initial thresholds ----
        float en[6];
#pragma unroll
        for (int t = 0; t < 6; ++t) en[t] = enorm_g[t * 16 + cl];
#pragma unroll
        for (int t = 0; t < 6; ++t) {
            const ushort* bp = &sbuf[0][(size_t)(t * 16 + cl) * DDIM];
            bf16x8 b0 = *(const bf16x8*)(bp + slot0);
            bf16x8 b1 = *(const bf16x8*)(bp + slot1);
            f32x4 d0 = __builtin_amdgcn_mfma_f32_16x16x32_bf16(a00, b0, z4, 0, 0, 0);
            f32x4 d1 = __builtin_amdgcn_mfma_f32_16x16x32_bf16(a10, b0, z4, 0, 0, 0);
            d0 = __builtin_amdgcn_mfma_f32_16x16x32_bf16(a01, b1, d0, 0, 0, 0);
            d1 = __builtin_amdgcn_mfma_f32_16x16x32_bf16(a11, b1, d1, 0, 0, 0);
#pragma unroll
            for (int r = 0; r < 4; ++r) {
                rmin0[r] = fminf(rmin0[r], fmaf(-2.f, d0[r], en[t]));
                rmin1[r] = fminf(rmin1[r], fmaf(-2.f, d1[r], en[t]));
            }
        }
#pragma unroll
        for (int m = 1; m < 16; m <<= 1) {
#pragma unroll
            for (int r = 0; r < 4; ++r) {
                rmin0[r] = fminf(rmin0[r], __shfl_xor(rmin0[r], m, 64));
                rmin1[r] = fminf(rmin1[r], __shfl_xor(rmin1[r], m, 64));
            }
        }
#pragma unroll
        for (int r = 0; r < 4; ++r) { thrS0[r] = rmin0[r] + MARGIN; thrS1[r] = rmin1[r] + MARGIN; }
    }

    int cur = 0;
    for (int s = 0; s < NSTEP; ++s) {
        float4 n0, n1, n2;
        const bool more = (s + 1 < NSTEP);
        if (more) {   // issue-early: next chunk global loads
            const float4* src = (const float4*)(eh + (size_t)(s + 1) * CHUNK * DDIM);
            n0 = src[tid]; n1 = src[256 + tid]; n2 = src[512 + tid];
        }
        const int cb = s * CHUNK;
        float en[6];
#pragma unroll
        for (int t = 0; t < 6; ++t) en[t] = enorm_g[cb + t * 16 + cl];

        // ---- hot loop: per tile MFMA -> score -> rmin + branchless mask ----
        unsigned m0 = 0, m1 = 0;   // bit t*4+r: candidate vs STALE threshold
#pragma unroll
        for (int t = 0; t < 6; ++t) {
            const ushort* bp = &sbuf[cur][(size_t)(t * 16 + cl) * DDIM];
            bf16x8 b0 = *(const bf16x8*)(bp + slot0);
            bf16x8 b1 = *(const bf16x8*)(bp + slot1);
            f32x4 d0 = __builtin_amdgcn_mfma_f32_16x16x32_bf16(a00, b0, z4, 0, 0, 0);
            f32x4 d1 = __builtin_amdgcn_mfma_f32_16x16x32_bf16(a10, b0, z4, 0, 0, 0);
            d0 = __builtin_amdgcn_mfma_f32_16x16x32_bf16(a01, b1, d0, 0, 0, 0);
            d1 = __builtin_amdgcn_mfma_f32_16x16x32_bf16(a11, b1, d1, 0, 0, 0);
            float en_ = en[t];
#pragma unroll
            for (int r = 0; r < 4; ++r) {
                float s0_ = fmaf(-2.f, d0[r], en_);
                float s1_ = fmaf(-2.f, d1[r], en_);
                rmin0[r] = fminf(rmin0[r], s0_);
                rmin1[r] = fminf(rmin1[r], s1_);
                m0 |= (unsigned)(s0_ <= thrS0[r]) << (t * 4 + r);
                m1 |= (unsigned)(s1_ <= thrS1[r]) << (t * 4 + r);
            }
        }
        // reduce rmin for the NEXT chunk's threshold (off TEST's path)
#pragma unroll
        for (int m = 1; m < 16; m <<= 1) {
#pragma unroll
            for (int r = 0; r < 4; ++r) {
                rmin0[r] = fminf(rmin0[r], __shfl_xor(rmin0[r], m, 64));
                rmin1[r] = fminf(rmin1[r], __shfl_xor(rmin1[r], m, 64));
            }
        }
        if (more) {   // write-late into the other buffer
            *(float4*)&sbuf[cur ^ 1][(size_t)tid * 8]         = n0;
            *(float4*)&sbuf[cur ^ 1][(size_t)(256 + tid) * 8] = n1;
            *(float4*)&sbuf[cur ^ 1][(size_t)(512 + tid) * 8] = n2;
        }
        __syncthreads();
        // ---- sparse TEST: iterate rare set bits (regs + own wq slice only) ----
        while (m0) {
            int b = __ffs(m0) - 1; m0 &= m0 - 1;
            int t = b >> 2, r = b & 3;
            int c = cb + t * 16 + cl;
            if (c < NUM_CODES) {
                unsigned i_ = atomicAdd(&qcnt[w][g*4 + r], 1u);
                if (i_ < SLOTS) wq[w][(g*4 + r) * SLOTS + i_] = (ushort)c;
            }
        }
        while (m1) {
            int b = __ffs(m1) - 1; m1 &= m1 - 1;
            int t = b >> 2, r = b & 3;
            int c = cb + t * 16 + cl;
            if (c < NUM_CODES) {
                unsigned i_ = atomicAdd(&qcnt[w][16 + g*4 + r], 1u);
                if (i_ < SLOTS) wq[w][(16 + g*4 + r) * SLOTS + i_] = (ushort)c;
            }
        }
        // tighten thresholds for next chunk
#pragma unroll
        for (int r = 0; r < 4; ++r) { thrS0[r] = rmin0[r] + MARGIN; thrS1[r] = rmin1[r] + MARGIN; }
        cur ^= 1;
    }

    // ---- exact rescore (reference chain, bit-identical argmin) ----
    auto exact_pk = [&](int c, long gq) -> unsigned long long {
        const float* xr = x + gq * DDIM;
        const float* er = emb + (size_t)c * DDIM;
        float dot = 0.f;
#pragma unroll
        for (int p4 = 0; p4 < 16; ++p4) {
            float4 xv = *(const float4*)(xr + 4 * p4);
            float4 ev = *(const float4*)(er + 4 * p4);
            dot = fmaf(xv.x, ev.x, dot); dot = fmaf(xv.y, ev.y, dot);
            dot = fmaf(xv.z, ev.z, dot); dot = fmaf(xv.w, ev.w, dot);
        }
        float dist = (xnorm[gq] + enorm_g[c]) - 2.f * dot;   // reference rounding order
        unsigned u = __float_as_uint(dist);
        unsigned key = (u & 0x80000000u) ? ~u : (u | 0x80000000u);  // monotone map
        return ((unsigned long long)key << 32) | (unsigned)c;       // lex (dist, c)
    };

    // 8 groups x 8 lanes: 8 queries rescored in parallel
    const int grp = lane >> 3, gl = lane & 7;
#pragma unroll
    for (int qo = 0; qo < 4; ++qo) {
        const int ql = qo * 8 + grp;
        const long gq = qw + ql;
        const unsigned nq = qcnt[w][ql];
        unsigned long long pk = ~0ULL;
        if (nq <= SLOTS) {
            for (unsigned i = gl; i < nq; i += 8) {
                unsigned long long t = exact_pk((int)wq[w][ql * SLOTS + i], gq);
                if (t < pk) pk = t;
            }
        }
#pragma unroll
        for (int m = 1; m < 8; m <<= 1) {
            unsigned long long o = (unsigned long long)__shfl_xor((long long)pk, m, 64);
            if (o < pk) pk = o;
        }
        if (gl == 0 && nq <= SLOTS) {
            skk[w][ql] = (unsigned)pk;
            out[gq] = (float)(unsigned)pk;      // codes as float values
        }
    }
    // overflow fallback (rare): exact full scan, full wave per query
    for (int ql = 0; ql < QPW; ++ql) {
        if (qcnt[w][ql] <= SLOTS) continue;
        const long gq = qw + ql;
        unsigned long long pk = ~0ULL;
        for (int t = 0; t < 21; ++t) {
            int c = lane + (t << 6);
            if (c < NUM_CODES) {
                unsigned long long tp = exact_pk(c, gq);
                if (tp < pk) pk = tp;
            }
        }
#pragma unroll
        for (int m = 1; m < 64; m <<= 1) {
            unsigned long long o = (unsigned long long)__shfl_xor((long long)pk, m, 64);
            if (o < pk) pk = o;
        }
        if (lane == 0) {
            skk[w][ql] = (unsigned)pk;
            out[gq] = (float)(unsigned)pk;
        }
    }

    // ---- gather embedding rows: 4 units x 16 lanes ----
    const int gu = lane >> 4, gv = lane & 15;
#pragma unroll
    for (int qo = 0; qo < 8; ++qo) {
        const int ql = qo * 4 + gu;
        const unsigned kk = skk[w][ql];
        const long gq = qw + ql;
        *(float4*)(out + (long)NUM_Q + gq * DDIM + gv * 4) =
            *(const float4*)(emb + (size_t)kk * DDIM + gv * 4);
    }
}

extern "C" void kernel_launch(void* const* d_in, const int* in_sizes, int n_in,
                              void* d_out, int out_size, void* d_ws, size_t ws_size,
                              hipStream_t stream) {
    const float* x   = (const float*)d_in[0];
    const float* emb = (const float*)d_in[1];
    float*  enorm = (float*)d_ws;                      // 5376 B (pad to 8192)
    float*  xnorm = (float*)((char*)d_ws + 8192);      // 524288 B
    ushort* eh    = (ushort*)((char*)d_ws + 532480);   // 172032 B (16B-aligned)

    hipLaunchKernelGGL(vq_prep, dim3(PAD_CODES / 64), dim3(64), 0, stream,
                       emb, enorm, eh);
    hipLaunchKernelGGL(vq_xnorm, dim3(NUM_Q / 256), dim3(256), 0, stream,
                       x, xnorm);
    hipLaunchKernelGGL(vq_main, dim3(NUM_Q / QPB), dim3(THREADS), 0, stream,
                       x, emb, enorm, xnorm, eh, (float*)d_out);
}

// Round 24
// 127.657 us; speedup vs baseline: 1.2190x; 1.2190x over previous
//
#include <hip/hip_runtime.h>

#define NUM_CODES 1296
#define PAD_CODES 1344    // 14 chunks * 96 (pads duplicate code 1295)
#define DDIM 64
#define NUM_Q 131072      // 32*64*64
#define THREADS 256       // 4 waves
#define QPW 32            // queries per wave
#define QPB 128           // queries per block; 1024 blocks
#define MARGIN 0.25f      // certified: 2*alpha <= 0.16 (bf16 screen) + headroom
#define SLOTS 16          // per-query candidate slots (overflow -> exact scan)
#define CHUNK 96          // codes per LDS chunk (12288 B)
#define NSTEP 14          // PAD_CODES / CHUNK
#define SXP 68            // sx row pitch in floats (68%32=4 -> 2-way banks; 272B row, 16B-aligned)

typedef __attribute__((ext_vector_type(8))) short bf16x8;
typedef __attribute__((ext_vector_type(4))) float f32x4;

__device__ __forceinline__ ushort f2bf(float f) {   // fp32 -> bf16 RNE
    unsigned u = __float_as_uint(f);
    return (ushort)((u + 0x7fffu + ((u >> 16) & 1u)) >> 16);
}

// enorm (exact numpy pairwise chain) + bf16 embeddings, slot-swizzled:
// 16B slot s (0..7) of code k stored at halfword k*64 + (s^(k&7))*8.
__global__ __launch_bounds__(64) void vq_prep(const float* __restrict__ emb,
                                              float* __restrict__ enorm,
                                              ushort* __restrict__ eh) {
    int k = blockIdx.x * 64 + threadIdx.x;
    if (k >= PAD_CODES) return;
    int ks = k < NUM_CODES ? k : NUM_CODES - 1;
    const float* e = emb + (size_t)ks * DDIM;
    float f[DDIM];
#pragma unroll
    for (int i = 0; i < 16; ++i) {
        float4 v = *(const float4*)(e + 4 * i);
        f[4*i] = v.x; f[4*i+1] = v.y; f[4*i+2] = v.z; f[4*i+3] = v.w;
    }
    {
#pragma clang fp contract(off)
        float r8[8];
#pragma unroll
        for (int j = 0; j < 8; ++j) { float t = f[j] * f[j]; r8[j] = t; }
#pragma unroll
        for (int i = 1; i < 8; ++i) {
#pragma unroll
            for (int j = 0; j < 8; ++j) { float t = f[i*8+j] * f[i*8+j]; r8[j] += t; }
        }
        enorm[k] = ((r8[0]+r8[1])+(r8[2]+r8[3])) + ((r8[4]+r8[5])+(r8[6]+r8[7]));
    }
    ushort h[DDIM];
#pragma unroll
    for (int d = 0; d < DDIM; ++d) h[d] = f2bf(f[d]);
    uint* dh = (uint*)(eh + (size_t)k * DDIM);
#pragma unroll
    for (int s = 0; s < 8; ++s) {
        int ds = s ^ (k & 7);
#pragma unroll
        for (int j = 0; j < 4; ++j)
            dh[ds*4 + j] = (uint)h[s*8 + 2*j] | ((uint)h[s*8 + 2*j + 1] << 16);
    }
}

// Single-sweep LDS-staged bf16 MFMA screen + exact fp32 rescore.
// x block resident in LDS: A-frags, x1 norms, and rescore all read it there.
__global__ __launch_bounds__(THREADS) void vq_main(
        const float* __restrict__ x, const float* __restrict__ emb,
        const float* __restrict__ enorm_g, const ushort* __restrict__ eh,
        float* __restrict__ out) {
    __shared__ ushort sbuf[2][CHUNK * DDIM];        // 24576 B
    __shared__ float sx[QPB * SXP];                 // 34816 B (x rows, fp32)
    __shared__ float sen[PAD_CODES];                // 5376 B
    __shared__ float x1s[QPB];                      // 512 B
    __shared__ ushort wq[4][QPW * SLOTS];           // 4096 B
    __shared__ unsigned qcnt[4][QPW];               // 512 B
    __shared__ unsigned skk[4][QPW];                // 512 B  -> total 70400 B

    const int tid  = threadIdx.x;
    const int lane = tid & 63;
    const int w    = tid >> 6;
    const int cl   = lane & 15;          // MFMA col = code-in-tile
    const int g    = lane >> 4;          // k-slice / D-row group
    const long qw  = (long)blockIdx.x * QPB + w * QPW;
    const int qloc0 = w * QPW;           // block-local query base of this wave

    if (lane < QPW) qcnt[w][lane] = 0;

    {   // prologue: stage x block (coalesced), chunk 0, enorm table
        const float4* xsrc = (const float4*)(x + (size_t)blockIdx.x * QPB * DDIM);
#pragma unroll
        for (int u = 0; u < 8; ++u) {
            int idx = u * THREADS + tid;
            int r = idx >> 4, j = idx & 15;
            *(float4*)&sx[r * SXP + j * 4] = xsrc[idx];
        }
        const float4* src = (const float4*)eh;
        float4 s0 = src[tid], s1 = src[256 + tid], s2 = src[512 + tid];
        *(float4*)&sbuf[0][(size_t)tid * 8]         = s0;
        *(float4*)&sbuf[0][(size_t)(256 + tid) * 8] = s1;
        *(float4*)&sbuf[0][(size_t)(512 + tid) * 8] = s2;
        for (int i = tid; i < PAD_CODES; i += THREADS) sen[i] = enorm_g[i];
    }
    __syncthreads();

    // ||x||^2 per query (exact numpy pairwise chain; inputs are exact fp32 x)
    if (tid < QPB) {
#pragma clang fp contract(off)
        float r8[8];
#pragma unroll
        for (int j = 0; j < 8; ++j) { float v = sx[tid*SXP + j]; float t = v*v; r8[j] = t; }
#pragma unroll
        for (int i = 1; i < 8; ++i) {
#pragma unroll
            for (int j = 0; j < 8; ++j) { float v = sx[tid*SXP + i*8 + j]; float t = v*v; r8[j] += t; }
        }
        x1s[tid] = ((r8[0]+r8[1])+(r8[2]+r8[3])) + ((r8[4]+r8[5])+(r8[6]+r8[7]));
    }

    // A-frags (persistent) from LDS: rows qloc0+cl / qloc0+16+cl; k g*8(+32)
    bf16x8 a00, a01, a10, a11;
    {
        const float* xr0 = &sx[(qloc0 + cl) * SXP + g * 8];
        const float* xr1 = xr0 + 16 * SXP;
#pragma unroll
        for (int j = 0; j < 8; ++j) {
            a00[j] = (short)f2bf(xr0[j]);
            a01[j] = (short)f2bf(xr0[j + 32]);
            a10[j] = (short)f2bf(xr1[j]);
            a11[j] = (short)f2bf(xr1[j + 32]);
        }
    }

    float rmin0[4], rmin1[4];
#pragma unroll
    for (int r = 0; r < 4; ++r) { rmin0[r] = __builtin_inff(); rmin1[r] = __builtin_inff(); }

    const int slot0 = (g     ^ (cl & 7)) * 8;   // swizzled halfword offsets
    const int slot1 = ((g+4) ^ (cl & 7)) * 8;
    const f32x4 z4 = {0.f, 0.f, 0.f, 0.f};

#define MFMA_TILE(T, D0, D1) { \
        const ushort* bp_ = &sbuf[cur][(size_t)((T) * 16 + cl) * DDIM]; \
        bf16x8 b0_ = *(const bf16x8*)(bp_ + slot0); \
        bf16x8 b1_ = *(const bf16x8*)(bp_ + slot1); \
        D0 = __builtin_amdgcn_mfma_f32_16x16x32_bf16(a00, b0_, z4, 0, 0, 0); \
        D1 = __builtin_amdgcn_mfma_f32_16x16x32_bf16(a10, b0_, z4, 0, 0, 0); \
        D0 = __builtin_amdgcn_mfma_f32_16x16x32_bf16(a01, b1_, D0, 0, 0, 0); \
        D1 = __builtin_amdgcn_mfma_f32_16x16x32_bf16(a11, b1_, D1, 0, 0, 0); }

#define SCORE_TILE(T, D0, D1) { \
        float en_ = sen[cb + (T) * 16 + cl]; \
        _Pragma("unroll") \
        for (int r = 0; r < 4; ++r) { \
            D0[r] = fmaf(-2.f, D0[r], en_); \
            D1[r] = fmaf(-2.f, D1[r], en_); \
            rmin0[r] = fminf(rmin0[r], D0[r]); \
            rmin1[r] = fminf(rmin1[r], D1[r]); } }

#define TEST_TILE(T, D0, D1) { \
        const int c_ = cb + (T) * 16 + cl; \
        if (c_ < NUM_CODES) { \
            _Pragma("unroll") \
            for (int r = 0; r < 4; ++r) { \
                if (D0[r] <= thr0[r]) { \
                    unsigned i_ = atomicAdd(&qcnt[w][g*4 + r], 1u); \
                    if (i_ < SLOTS) wq[w][(g*4 + r) * SLOTS + i_] = (ushort)c_; } \
                if (D1[r] <= thr1[r]) { \
                    unsigned i_ = atomicAdd(&qcnt[w][16 + g*4 + r], 1u); \
                    if (i_ < SLOTS) wq[w][(16 + g*4 + r) * SLOTS + i_] = (ushort)c_; } } } }

    int cur = 0;
    for (int s = 0; s < NSTEP; ++s) {
        float4 n0, n1, n2;
        const bool more = (s + 1 < NSTEP);
        if (more) {   // issue-early: next chunk global loads
            const float4* src = (const float4*)(eh + (size_t)(s + 1) * CHUNK * DDIM);
            n0 = src[tid]; n1 = src[256 + tid]; n2 = src[512 + tid];
        }
        const int cb = s * CHUNK;
        f32x4 d00, d01, d02, d03, d04, d05;   // 12 named acc regs (rule #20)
        f32x4 d10, d11, d12, d13, d14, d15;
        MFMA_TILE(0, d00, d10); MFMA_TILE(1, d01, d11); MFMA_TILE(2, d02, d12);
        MFMA_TILE(3, d03, d13); MFMA_TILE(4, d04, d14); MFMA_TILE(5, d05, d15);
        SCORE_TILE(0, d00, d10); SCORE_TILE(1, d01, d11); SCORE_TILE(2, d02, d12);
        SCORE_TILE(3, d03, d13); SCORE_TILE(4, d04, d14); SCORE_TILE(5, d05, d15);
        // one cross-col reduce per chunk (16 lanes share a query row)
#pragma unroll
        for (int m = 1; m < 16; m <<= 1) {
#pragma unroll
            for (int r = 0; r < 4; ++r) {
                rmin0[r] = fminf(rmin0[r], __shfl_xor(rmin0[r], m, 64));
                rmin1[r] = fminf(rmin1[r], __shfl_xor(rmin1[r], m, 64));
            }
        }
        float thr0[4], thr1[4];
#pragma unroll
        for (int r = 0; r < 4; ++r) { thr0[r] = rmin0[r] + MARGIN; thr1[r] = rmin1[r] + MARGIN; }
        if (more) {   // write-late into the other buffer
            *(float4*)&sbuf[cur ^ 1][(size_t)tid * 8]         = n0;
            *(float4*)&sbuf[cur ^ 1][(size_t)(256 + tid) * 8] = n1;
            *(float4*)&sbuf[cur ^ 1][(size_t)(512 + tid) * 8] = n2;
        }
        __syncthreads();
        TEST_TILE(0, d00, d10); TEST_TILE(1, d01, d11); TEST_TILE(2, d02, d12);
        TEST_TILE(3, d03, d13); TEST_TILE(4, d04, d14); TEST_TILE(5, d05, d15);
        cur ^= 1;
    }

    // ---- exact rescore (reference chain, bit-identical argmin); x from LDS ----
    auto exact_pk = [&](int c, int qloc) -> unsigned long long {
        const float* xr = &sx[qloc * SXP];
        const float* er = emb + (size_t)c * DDIM;
        float dot = 0.f;
#pragma unroll
        for (int p4 = 0; p4 < 16; ++p4) {
            float4 xv = *(const float4*)(xr + 4 * p4);
            float4 ev = *(const float4*)(er + 4 * p4);
            dot = fmaf(xv.x, ev.x, dot); dot = fmaf(xv.y, ev.y, dot);
            dot = fmaf(xv.z, ev.z, dot); dot = fmaf(xv.w, ev.w, dot);
        }
        float dist = (x1s[qloc] + sen[c]) - 2.f * dot;   // reference rounding order
        unsigned u = __float_as_uint(dist);
        unsigned key = (u & 0x80000000u) ? ~u : (u | 0x80000000u);  // monotone map
        return ((unsigned long long)key << 32) | (unsigned)c;       // lex (dist, c)
    };

    // 8 groups x 8 lanes: 8 queries rescored in parallel
    const int grp = lane >> 3, gl = lane & 7;
#pragma unroll
    for (int qo = 0; qo < 4; ++qo) {
        const int ql = qo * 8 + grp;
        const unsigned nq = qcnt[w][ql];
        unsigned long long pk = ~0ULL;
        if (nq <= SLOTS) {
            for (unsigned i = gl; i < nq; i += 8) {
                unsigned long long t = exact_pk((int)wq[w][ql * SLOTS + i], qloc0 + ql);
                if (t < pk) pk = t;
            }
        }
#pragma unroll
        for (int m = 1; m < 8; m <<= 1) {
            unsigned long long o = (unsigned long long)__shfl_xor((long long)pk, m, 64);
            if (o < pk) pk = o;
        }
        if (gl == 0 && nq <= SLOTS) {
            skk[w][ql] = (unsigned)pk;
            out[qw + ql] = (float)(unsigned)pk;   // codes as float values
        }
    }
    // overflow fallback (rare): exact full scan, full wave per query
    for (int ql = 0; ql < QPW; ++ql) {
        if (qcnt[w][ql] <= SLOTS) continue;
        unsigned long long pk = ~0ULL;
        for (int t = 0; t < 21; ++t) {
            int c = lane + (t << 6);
            if (c < NUM_CODES) {
                unsigned long long tp = exact_pk(c, qloc0 + ql);
                if (tp < pk) pk = tp;
            }
        }
#pragma unroll
        for (int m = 1; m < 64; m <<= 1) {
            unsigned long long o = (unsigned long long)__shfl_xor((long long)pk, m, 64);
            if (o < pk) pk = o;
        }
        if (lane == 0) {
            skk[w][ql] = (unsigned)pk;
            out[qw + ql] = (float)(unsigned)pk;
        }
    }

    // ---- gather embedding rows: 4 units x 16 lanes ----
    const int gu = lane >> 4, gv = lane & 15;
#pragma unroll
    for (int qo = 0; qo < 8; ++qo) {
        const int ql = qo * 4 + gu;
        const unsigned kk = skk[w][ql];
        const long gq = qw + ql;
        *(float4*)(out + (long)NUM_Q + gq * DDIM + gv * 4) =
            *(const float4*)(emb + (size_t)kk * DDIM + gv * 4);
    }
}

extern "C" void kernel_launch(void* const* d_in, const int* in_sizes, int n_in,
                              void* d_out, int out_size, void* d_ws, size_t ws_size,
                              hipStream_t stream) {
    const float* x   = (const float*)d_in[0];
    const float* emb = (const float*)d_in[1];
    float*  enorm = (float*)d_ws;                      // 5376 B (pad to 8192)
    ushort* eh    = (ushort*)((char*)d_ws + 8192);     // 172032 B (16B-aligned)

    hipLaunchKernelGGL(vq_prep, dim3(PAD_CODES / 64), dim3(64), 0, stream,
                       emb, enorm, eh);
    hipLaunchKernelGGL(vq_main, dim3(NUM_Q / QPB), dim3(THREADS), 0, stream,
                       x, emb, enorm, eh, (float*)d_out);
}